// Round 7
// baseline (1921.948 us; speedup 1.0000x reference)
//
#include <hip/hip_runtime.h>
#include <math.h>

#define NTOK 65536
#define DMODEL 256
#define DI 512
#define DS 16
#define CHUNK 128
#define NCHUNK (NTOK / CHUNK)   // 512
#define QCH 128                 // channels per scan quarter

typedef __bf16 bf16x8 __attribute__((ext_vector_type(8)));
typedef float  f32x4  __attribute__((ext_vector_type(4)));

__device__ __forceinline__ float sigf(float x) { return 1.0f / (1.0f + expf(-x)); }

// ---------------------------------------------------------------------------
// wprep_kernel: split the two used 512x512 blocks of gg2_w into hi/lo bf16,
// fragment packet order (verified round 1/2).
// ---------------------------------------------------------------------------
__global__ __launch_bounds__(256) void wprep_kernel(
    const float* gg2_w, unsigned short* Wg)
{
    int p = blockIdx.x * 256 + threadIdx.x;   // 0 .. 131071
    int lg = p & 3;
    int c  = (p >> 2) & 511;
    int hl = (p >> 11) & 1;
    int kc = (p >> 12) & 15;
    int gm = p >> 16;
    int row = gm * 1024 + c;
    const float* src = gg2_w + (size_t)row * 512 + kc * 32 + lg * 8;
    union { unsigned short u[8]; float4 f; } outv;
#pragma unroll
    for (int j = 0; j < 8; j++) {
        float x = src[j];
        __bf16 h = (__bf16)x;
        union { __bf16 b; unsigned short us; } cv;
        if (hl) cv.b = (__bf16)(x - (float)h); else cv.b = h;
        outv.u[j] = cv.us;
    }
    *(float4*)(Wg + (size_t)p * 8) = outv.f;
}

// ---------------------------------------------------------------------------
// wprep_inproj: split in_proj_w (1024 x 256), fragment order (verified r2).
// ---------------------------------------------------------------------------
__global__ __launch_bounds__(256) void wprep_inproj(
    const float* in_proj_w, unsigned short* Wg2)
{
    int p = blockIdx.x * 256 + threadIdx.x;   // 0 .. 65535
    int lg = p & 3;
    int c  = (p >> 2) & 511;
    int hl = (p >> 11) & 1;
    int kc = (p >> 12) & 7;
    int gm = p >> 15;
    const float* src = in_proj_w + (size_t)(gm * 512 + c) * 256 + kc * 32 + lg * 8;
    union { unsigned short u[8]; float4 f; } outv;
#pragma unroll
    for (int j = 0; j < 8; j++) {
        float x = src[j];
        __bf16 h = (__bf16)x;
        union { __bf16 b; unsigned short us; } cv;
        if (hl) cv.b = (__bf16)(x - (float)h); else cv.b = h;
        outv.u[j] = cv.us;
    }
    *(float4*)(Wg2 + (size_t)p * 8) = outv.f;
}

// ---------------------------------------------------------------------------
// wprep_dt: split dt_proj_w (512 x 512) into hi/lo bf16 packets, per-quarter.
// ---------------------------------------------------------------------------
__global__ __launch_bounds__(256) void wprep_dt(
    const float* dt_proj_w, unsigned short* Wdt)
{
    int p = blockIdx.x * 256 + threadIdx.x;   // 0 .. 65535
    int lg = p & 3;
    int c  = (p >> 2) & 127;
    int hl = (p >> 9) & 1;
    int kc = (p >> 10) & 15;
    int q  = p >> 14;
    const float* src = dt_proj_w + (size_t)(q * 128 + c) * 512 + kc * 32 + lg * 8;
    union { unsigned short u[8]; float4 f; } outv;
#pragma unroll
    for (int j = 0; j < 8; j++) {
        float x = src[j];
        __bf16 h = (__bf16)x;
        union { __bf16 b; unsigned short us; } cv;
        if (hl) cv.b = (__bf16)(x - (float)h); else cv.b = h;
        outv.u[j] = cv.us;
    }
    *(float4*)(Wdt + (size_t)p * 8) = outv.f;
}

// ---------------------------------------------------------------------------
// wprep_out: split out_proj_w (256 x 512) into hi/lo bf16 packets.
// Written into the (then-dead) head of P1 just before the final GEMM.
// ---------------------------------------------------------------------------
__global__ __launch_bounds__(256) void wprep_out(
    const float* out_proj_w, unsigned short* Wout)
{
    int p = blockIdx.x * 256 + threadIdx.x;   // 0 .. 32767
    int lg = p & 3;
    int c  = (p >> 2) & 255;
    int hl = (p >> 10) & 1;
    int kc = p >> 11;
    const float* src = out_proj_w + (size_t)c * 512 + kc * 32 + lg * 8;
    union { unsigned short u[8]; float4 f; } outv;
#pragma unroll
    for (int j = 0; j < 8; j++) {
        float x = src[j];
        __bf16 h = (__bf16)x;
        union { __bf16 b; unsigned short us; } cv;
        if (hl) cv.b = (__bf16)(x - (float)h); else cv.b = h;
        outv.u[j] = cv.us;
    }
    *(float4*)(Wout + (size_t)p * 8) = outv.f;
}

// ---------------------------------------------------------------------------
// in_conv_mfma: bf16x3 streaming-MFMA in_proj + conv + silu (round-3 verified)
// LDS 80 KiB -> already 2 blocks/CU. Unchanged.
// ---------------------------------------------------------------------------
#define MFMA_CHUNK(NFM, KC, WH, WL)                                           \
    _Pragma("unroll")                                                         \
    for (int fm = 0; fm < NFM; fm++) {                                        \
        int t = (fm < 4) ? (fm * 16 + lr) : (64 + lr);                        \
        int pidx = (t * 32 + (((KC) * 4 + lg) ^ (t & 7))) * 8;                \
        bf16x8 ah = *(const bf16x8*)&AhL[pidx];                               \
        bf16x8 al = *(const bf16x8*)&AlL[pidx];                               \
        _Pragma("unroll")                                                     \
        for (int fn = 0; fn < 4; fn++) {                                      \
            acc[fm][fn] = __builtin_amdgcn_mfma_f32_16x16x32_bf16(ah, WH[fn], acc[fm][fn], 0, 0, 0); \
            acc[fm][fn] = __builtin_amdgcn_mfma_f32_16x16x32_bf16(ah, WL[fn], acc[fm][fn], 0, 0, 0); \
            acc[fm][fn] = __builtin_amdgcn_mfma_f32_16x16x32_bf16(al, WH[fn], acc[fm][fn], 0, 0, 0); \
        }                                                                     \
    }

__global__ __launch_bounds__(512, 2) void in_conv_mfma(
    const float* x, const unsigned short* Wg2, const float* conv_w,
    const float* conv_b, float* P1, float* P2)
{
    __shared__ __align__(16) unsigned short smem[2 * 80 * 256];  // 80 KiB
    unsigned short* AhL = smem;
    unsigned short* AlL = smem + 80 * 256;
    float* xs = (float*)smem;          // repurposed: [8 waves][68][33] fp32

    const int tid = threadIdx.x;
    const int row0 = blockIdx.x * 64;
    const int l  = tid & 63;
    const int wn = tid >> 6;           // wave id / col-slice
    const int lr = l & 15;
    const int lg = l >> 4;

    // ---- Phase A: stage x split hi/lo (rows 0..63 main, 64..67 halo, rest 0)
    for (int i = tid; i < 80 * 32; i += 512) {
        int t = i >> 5, k8 = i & 31;
        float xv[8];
#pragma unroll
        for (int j = 0; j < 8; j++) xv[j] = 0.f;
        if (t < 68) {
            int gr = (t < 64) ? (row0 + t) : (row0 - 68 + t);
            if (gr >= 0) {
                float4 a0 = *(const float4*)(x + (size_t)gr * 256 + k8 * 8);
                float4 a1 = *(const float4*)(x + (size_t)gr * 256 + k8 * 8 + 4);
                xv[0]=a0.x; xv[1]=a0.y; xv[2]=a0.z; xv[3]=a0.w;
                xv[4]=a1.x; xv[5]=a1.y; xv[6]=a1.z; xv[7]=a1.w;
            }
        }
        bf16x8 ho, lo;
#pragma unroll
        for (int j = 0; j < 8; j++) {
            __bf16 hh = (__bf16)xv[j];
            ho[j] = hh;
            lo[j] = (__bf16)(xv[j] - (float)hh);
        }
        int pidx = (t * 32 + (k8 ^ (t & 7))) * 8;
        *(bf16x8*)&AhL[pidx] = ho;
        *(bf16x8*)&AlL[pidx] = lo;
    }
    __syncthreads();

    auto loadW = [&](int gm, int kc, bf16x8 (&wh)[4], bf16x8 (&wl)[4]) {
        const unsigned short* bh = Wg2 + (size_t)(((gm * 8 + kc) * 2 + 0) * 2048) * 8;
        const unsigned short* bl = Wg2 + (size_t)(((gm * 8 + kc) * 2 + 1) * 2048) * 8;
        const int pk = (wn * 64 + lr) * 4 + lg;
#pragma unroll
        for (int fn = 0; fn < 4; fn++) {
            wh[fn] = *(const bf16x8*)(bh + (size_t)(pk + fn * 64) * 8);
            wl[fn] = *(const bf16x8*)(bl + (size_t)(pk + fn * 64) * 8);
        }
    };

    // ---- z half (gm=1): 4 fm tiles, direct silu epilogue ----
    {
        f32x4 acc[4][4];
#pragma unroll
        for (int fm = 0; fm < 4; fm++)
#pragma unroll
            for (int fn = 0; fn < 4; fn++)
                acc[fm][fn] = (f32x4){0.f, 0.f, 0.f, 0.f};
        bf16x8 whA[4], wlA[4], whB[4], wlB[4];
        loadW(1, 0, whA, wlA);
#pragma unroll
        for (int kc = 0; kc < 8; kc += 2) {
            loadW(1, kc + 1, whB, wlB);
            MFMA_CHUNK(4, kc, whA, wlA)
            if (kc + 2 < 8) loadW(1, kc + 2, whA, wlA);
            MFMA_CHUNK(4, kc + 1, whB, wlB)
        }
#pragma unroll
        for (int fm = 0; fm < 4; fm++)
#pragma unroll
            for (int fn = 0; fn < 4; fn++) {
                int col = wn * 64 + fn * 16 + lr;
#pragma unroll
                for (int q = 0; q < 4; q++) {
                    int r = row0 + fm * 16 + lg * 4 + q;
                    float vz = acc[fm][fn][q];
                    P2[(size_t)r * 512 + col] = vz * sigf(vz);
                }
            }
    }

    // ---- x_in half (gm=0): 5 fm tiles (halo), conv epilogue ----
    {
        f32x4 acc[5][4];
#pragma unroll
        for (int fm = 0; fm < 5; fm++)
#pragma unroll
            for (int fn = 0; fn < 4; fn++)
                acc[fm][fn] = (f32x4){0.f, 0.f, 0.f, 0.f};
        bf16x8 whA[4], wlA[4], whB[4], wlB[4];
        loadW(0, 0, whA, wlA);
#pragma unroll
        for (int kc = 0; kc < 8; kc += 2) {
            loadW(0, kc + 1, whB, wlB);
            MFMA_CHUNK(5, kc, whA, wlA)
            if (kc + 2 < 8) loadW(0, kc + 2, whA, wlA);
            MFMA_CHUNK(5, kc + 1, whB, wlB)
        }

        __syncthreads();                       // all waves done reading A-LDS
        float* xsw = xs + wn * (68 * 33);      // per-wave slab (wave-private)
        const int c_local = l & 31;
        const int rbase = (l >> 5) * 32;
#pragma unroll
        for (int h = 0; h < 2; h++) {
            if (h) __syncthreads();            // uniform; protects slab reuse
#pragma unroll
            for (int fm = 0; fm < 5; fm++)
#pragma unroll
                for (int ff = 0; ff < 2; ff++) {
                    int fn = h * 2 + ff;
#pragma unroll
                    for (int q = 0; q < 4; q++) {
                        if (fm < 4) {
                            int rr = 4 + fm * 16 + lg * 4 + q;
                            xsw[rr * 33 + ff * 16 + lr] = acc[fm][fn][q];
                        } else if (lg == 0) {
                            xsw[q * 33 + ff * 16 + lr] = acc[fm][fn][q];
                        }
                    }
                }
            asm volatile("s_waitcnt lgkmcnt(0)" ::: "memory");
            int cg = wn * 64 + h * 32 + c_local;
            float w0 = conv_w[cg * 4 + 0], w1 = conv_w[cg * 4 + 1];
            float w2 = conv_w[cg * 4 + 2], w3 = conv_w[cg * 4 + 3];
            float cb = conv_b[cg];
            float s0 = xsw[(rbase + 1) * 33 + c_local];
            float s1 = xsw[(rbase + 2) * 33 + c_local];
            float s2 = xsw[(rbase + 3) * 33 + c_local];
#pragma unroll
            for (int i = 0; i < 32; i++) {
                float s3 = xsw[(rbase + 4 + i) * 33 + c_local];
                float cv = cb + w0 * s0 + w1 * s1 + w2 * s2 + w3 * s3;
                cv = cv * sigf(cv);
                P1[(size_t)(row0 + rbase + i) * 512 + cg] = cv;
                s0 = s1; s1 = s2; s2 = s3;
            }
        }
    }
}

// ---------------------------------------------------------------------------
// gates_mfma_kernel v3: occupancy-doubled.
//   grid.y = gm (each block one gate GEMM); K-half staged LDS (64 KiB + red);
//   Phase A = value-free LN-statistics pass; each K-half recomputes its 32
//   dims (3 fma + LN + gelu) just before staging -> no v[64] register array.
//   Single-buffered W (4 waves/SIMD hide the load latency).
// ---------------------------------------------------------------------------
__global__ __launch_bounds__(512, 4) void gates_mfma_kernel(
    const float* guidance, const float* gg1_w, const float* gg1_b,
    const float* ln_g, const float* ln_b,
    const unsigned short* Wg, const float* gg2_b,
    float* P1, float* P2)
{
    __shared__ __align__(16) unsigned short AhL[64 * 256];  // 32 KiB
    __shared__ __align__(16) unsigned short AlL[64 * 256];  // 32 KiB
    __shared__ float red_s[64][9], red_q[64][9];            // 4.5 KiB

    const int tid = threadIdx.x;
    const int tok = tid & 63;
    const int o   = tid >> 6;        // 0..7 == wave id
    const int row0 = blockIdx.x * 64;
    const int gm  = blockIdx.y;      // 0 = gate_in (P1), 1 = gate_out (P2)

    // ---- Phase A: LN statistics only (values recomputed per K-half) ----
    float g0 = guidance[(size_t)(row0 + tok) * 3 + 0];
    float g1 = guidance[(size_t)(row0 + tok) * 3 + 1];
    float g2 = guidance[(size_t)(row0 + tok) * 3 + 2];
    float sum = 0.f, sumsq = 0.f;
#pragma unroll
    for (int m = 0; m < 8; m++)
#pragma unroll
        for (int jj = 0; jj < 8; jj++) {
            int d = m * 64 + o * 8 + jj;
            float t = gg1_w[d * 3 + 0] * g0 + gg1_w[d * 3 + 1] * g1 +
                      gg1_w[d * 3 + 2] * g2 + gg1_b[d];
            sum += t; sumsq += t * t;
        }
    red_s[tok][o] = sum; red_q[tok][o] = sumsq;
    __syncthreads();
    sum = 0.f; sumsq = 0.f;
#pragma unroll
    for (int oo = 0; oo < 8; oo++) { sum += red_s[tok][oo]; sumsq += red_q[tok][oo]; }
    float mu = sum * (1.f / 512.f);
    float var = fmaxf(sumsq * (1.f / 512.f) - mu * mu, 0.f);
    float rstd = 1.f / sqrtf(var + 1e-5f);

    const int l  = tid & 63;
    const int wn = tid >> 6;
    const int lr = l & 15;
    const int lg = l >> 4;

    f32x4 acc[4][4];
#pragma unroll
    for (int fm = 0; fm < 4; fm++)
#pragma unroll
        for (int fn = 0; fn < 4; fn++)
            acc[fm][fn] = (f32x4){0.f, 0.f, 0.f, 0.f};

    for (int kh = 0; kh < 2; kh++) {
        __syncthreads();    // all waves done with previous half / LN reduce
        // ---- stage half kh: recompute 32 dims, gelu, split, packet write ----
#pragma unroll
        for (int mm = 0; mm < 4; mm++) {
            int m = kh * 4 + mm;
            bf16x8 hoct, loct;
#pragma unroll
            for (int jj = 0; jj < 8; jj++) {
                int d = m * 64 + o * 8 + jj;
                float t = gg1_w[d * 3 + 0] * g0 + gg1_w[d * 3 + 1] * g1 +
                          gg1_w[d * 3 + 2] * g2 + gg1_b[d];
                t = (t - mu) * rstd * ln_g[d] + ln_b[d];
                t = 0.5f * t * (1.f + erff(t * 0.70710678118654752440f));
                __bf16 h = (__bf16)t;
                hoct[jj] = h;
                loct[jj] = (__bf16)(t - (float)h);
            }
            int k8l = mm * 8 + o;    // local octet 0..31 within half
            int pidx = (tok * 32 + (k8l ^ (tok & 7))) * 8;
            *(bf16x8*)&AhL[pidx] = hoct;
            *(bf16x8*)&AlL[pidx] = loct;
        }
        __syncthreads();
        // ---- compute: kc 0..7 (global kc = kh*8+kc), single-buffered W ----
        for (int kc = 0; kc < 8; kc++) {
            bf16x8 wh[4], wl[4];
            {
                int kcg = kh * 8 + kc;
                const unsigned short* bh = Wg + (size_t)(((gm * 16 + kcg) * 2 + 0) * 2048) * 8;
                const unsigned short* bl = Wg + (size_t)(((gm * 16 + kcg) * 2 + 1) * 2048) * 8;
                int pk = (wn * 64 + lr) * 4 + lg;
#pragma unroll
                for (int fn = 0; fn < 4; fn++) {
                    wh[fn] = *(const bf16x8*)(bh + (size_t)(pk + fn * 64) * 8);
                    wl[fn] = *(const bf16x8*)(bl + (size_t)(pk + fn * 64) * 8);
                }
            }
#pragma unroll
            for (int fm = 0; fm < 4; fm++) {
                int t = fm * 16 + lr;
                int pidx = (t * 32 + ((kc * 4 + lg) ^ (t & 7))) * 8;
                bf16x8 ah = *(const bf16x8*)&AhL[pidx];
                bf16x8 al = *(const bf16x8*)&AlL[pidx];
#pragma unroll
                for (int fn = 0; fn < 4; fn++) {
                    acc[fm][fn] = __builtin_amdgcn_mfma_f32_16x16x32_bf16(
                        ah, wh[fn], acc[fm][fn], 0, 0, 0);
                    acc[fm][fn] = __builtin_amdgcn_mfma_f32_16x16x32_bf16(
                        ah, wl[fn], acc[fm][fn], 0, 0, 0);
                    acc[fm][fn] = __builtin_amdgcn_mfma_f32_16x16x32_bf16(
                        al, wh[fn], acc[fm][fn], 0, 0, 0);
                }
            }
        }
    }

    // ---- epilogue: C/D layout col = lane&15, row = (lane>>4)*4 + reg ----
    float* P = gm ? P2 : P1;
    const float* bias = gg2_b + gm * 1024;
#pragma unroll
    for (int fm = 0; fm < 4; fm++)
#pragma unroll
        for (int fn = 0; fn < 4; fn++) {
            int col = wn * 64 + fn * 16 + lr;
            float b = bias[col];
#pragma unroll
            for (int q = 0; q < 4; q++) {
                int r = row0 + fm * 16 + lg * 4 + q;
                size_t idx = (size_t)r * 512 + col;
                P[idx] *= sigf(acc[fm][fn][q] + b);
            }
        }
}

// ---------------------------------------------------------------------------
// dtp_mfma v2: K-half staged LDS (64 KiB) -> 2 blocks/CU, 4 waves/SIMD.
// ---------------------------------------------------------------------------
__global__ __launch_bounds__(512, 4) void dtp_mfma(
    const float* A, const unsigned short* Wdt, const float* bias,
    int dbase, float* delta_q)
{
    __shared__ __align__(16) unsigned short AhL[64 * 256];  // 32 KiB
    __shared__ __align__(16) unsigned short AlL[64 * 256];  // 32 KiB
    const int tid = threadIdx.x;
    const int row0 = blockIdx.x * 64;

    const int l  = tid & 63;
    const int wv = tid >> 6;
    const int wr = wv >> 2;          // 0..1  token half (32 rows)
    const int wc = wv & 3;           // 0..3  col quarter (32 cols)
    const int lr = l & 15;
    const int lg = l >> 4;
    const unsigned short* Wq = Wdt + (size_t)(dbase >> 7) * 16384 * 8;

    f32x4 acc[2][2];
#pragma unroll
    for (int fm = 0; fm < 2; fm++)
#pragma unroll
        for (int fn = 0; fn < 2; fn++)
            acc[fm][fn] = (f32x4){0.f, 0.f, 0.f, 0.f};

    for (int kh = 0; kh < 2; kh++) {
        if (kh) __syncthreads();
        for (int i = tid; i < 64 * 32; i += 512) {
            int t = i >> 5, k8 = i & 31;
            const float* src = A + (size_t)(row0 + t) * 512 + kh * 256 + k8 * 8;
            float4 a0 = *(const float4*)src, a1 = *(const float4*)(src + 4);
            float xv[8] = {a0.x, a0.y, a0.z, a0.w, a1.x, a1.y, a1.z, a1.w};
            bf16x8 ho, lo;
#pragma unroll
            for (int j = 0; j < 8; j++) {
                __bf16 hh = (__bf16)xv[j];
                ho[j] = hh;
                lo[j] = (__bf16)(xv[j] - (float)hh);
            }
            int pidx = (t * 32 + (k8 ^ (t & 7))) * 8;
            *(bf16x8*)&AhL[pidx] = ho;
            *(bf16x8*)&AlL[pidx] = lo;
        }
        __syncthreads();
        for (int kc = 0; kc < 8; kc++) {
            bf16x8 wh[2], wl[2];
            {
                int kcg = kh * 8 + kc;
                const unsigned short* bh = Wq + (size_t)((kcg * 2 + 0) * 512) * 8;
                const unsigned short* bl = Wq + (size_t)((kcg * 2 + 1) * 512) * 8;
                int pk = (wc * 32 + lr) * 4 + lg;
#pragma unroll
                for (int fn = 0; fn < 2; fn++) {
                    wh[fn] = *(const bf16x8*)(bh + (size_t)(pk + fn * 64) * 8);
                    wl[fn] = *(const bf16x8*)(bl + (size_t)(pk + fn * 64) * 8);
                }
            }
#pragma unroll
            for (int fm = 0; fm < 2; fm++) {
                int t = wr * 32 + fm * 16 + lr;
                int pidx = (t * 32 + ((kc * 4 + lg) ^ (t & 7))) * 8;
                bf16x8 ah = *(const bf16x8*)&AhL[pidx];
                bf16x8 al = *(const bf16x8*)&AlL[pidx];
#pragma unroll
                for (int fn = 0; fn < 2; fn++) {
                    acc[fm][fn] = __builtin_amdgcn_mfma_f32_16x16x32_bf16(
                        ah, wh[fn], acc[fm][fn], 0, 0, 0);
                    acc[fm][fn] = __builtin_amdgcn_mfma_f32_16x16x32_bf16(
                        ah, wl[fn], acc[fm][fn], 0, 0, 0);
                    acc[fm][fn] = __builtin_amdgcn_mfma_f32_16x16x32_bf16(
                        al, wh[fn], acc[fm][fn], 0, 0, 0);
                }
            }
        }
    }

#pragma unroll
    for (int fm = 0; fm < 2; fm++)
#pragma unroll
        for (int fn = 0; fn < 2; fn++) {
            int col = wc * 32 + fn * 16 + lr;
            float b = bias[dbase + col];
#pragma unroll
            for (int q = 0; q < 4; q++) {
                int r = row0 + wr * 32 + fm * 16 + lg * 4 + q;
                float s = acc[fm][fn][q] + b;
                delta_q[(size_t)r * 128 + col] =
                    fmaxf(s, 0.f) + log1pf(expf(-fabsf(s)));
            }
        }
}

// ---------------------------------------------------------------------------
// outp_mfma v2: K-half staged LDS (64 KiB) -> 2 blocks/CU, 4 waves/SIMD.
// ---------------------------------------------------------------------------
__global__ __launch_bounds__(512, 4) void outp_mfma(
    const float* A, const unsigned short* Wout, float* out)
{
    __shared__ __align__(16) unsigned short AhL[64 * 256];  // 32 KiB
    __shared__ __align__(16) unsigned short AlL[64 * 256];  // 32 KiB
    const int tid = threadIdx.x;
    const int row0 = blockIdx.x * 64;

    const int l  = tid & 63;
    const int wv = tid >> 6;
    const int wr = wv >> 2;          // 0..1  token half (32 rows)
    const int wc = wv & 3;           // 0..3  col slice (64 cols)
    const int lr = l & 15;
    const int lg = l >> 4;

    f32x4 acc[2][4];
#pragma unroll
    for (int fm = 0; fm < 2; fm++)
#pragma unroll
        for (int fn = 0; fn < 4; fn++)
            acc[fm][fn] = (f32x4){0.f, 0.f, 0.f, 0.f};

    for (int kh = 0; kh < 2; kh++) {
        if (kh) __syncthreads();
        for (int i = tid; i < 64 * 32; i += 512) {
            int t = i >> 5, k8 = i & 31;
            const float* src = A + (size_t)(row0 + t) * 512 + kh * 256 + k8 * 8;
            float4 a0 = *(const float4*)src, a1 = *(const float4*)(src + 4);
            float xv[8] = {a0.x, a0.y, a0.z, a0.w, a1.x, a1.y, a1.z, a1.w};
            bf16x8 ho, lo;
#pragma unroll
            for (int j = 0; j < 8; j++) {
                __bf16 hh = (__bf16)xv[j];
                ho[j] = hh;
                lo[j] = (__bf16)(xv[j] - (float)hh);
            }
            int pidx = (t * 32 + (k8 ^ (t & 7))) * 8;
            *(bf16x8*)&AhL[pidx] = ho;
            *(bf16x8*)&AlL[pidx] = lo;
        }
        __syncthreads();
        for (int kc = 0; kc < 8; kc++) {
            bf16x8 wh[4], wl[4];
            {
                int kcg = kh * 8 + kc;
                const unsigned short* bh = Wout + (size_t)((kcg * 2 + 0) * 1024) * 8;
                const unsigned short* bl = Wout + (size_t)((kcg * 2 + 1) * 1024) * 8;
                int pk = (wc * 64 + lr) * 4 + lg;
#pragma unroll
                for (int fn = 0; fn < 4; fn++) {
                    wh[fn] = *(const bf16x8*)(bh + (size_t)(pk + fn * 64) * 8);
                    wl[fn] = *(const bf16x8*)(bl + (size_t)(pk + fn * 64) * 8);
                }
            }
#pragma unroll
            for (int fm = 0; fm < 2; fm++) {
                int t = wr * 32 + fm * 16 + lr;
                int pidx = (t * 32 + ((kc * 4 + lg) ^ (t & 7))) * 8;
                bf16x8 ah = *(const bf16x8*)&AhL[pidx];
                bf16x8 al = *(const bf16x8*)&AlL[pidx];
#pragma unroll
                for (int fn = 0; fn < 4; fn++) {
                    acc[fm][fn] = __builtin_amdgcn_mfma_f32_16x16x32_bf16(
                        ah, wh[fn], acc[fm][fn], 0, 0, 0);
                    acc[fm][fn] = __builtin_amdgcn_mfma_f32_16x16x32_bf16(
                        ah, wl[fn], acc[fm][fn], 0, 0, 0);
                    acc[fm][fn] = __builtin_amdgcn_mfma_f32_16x16x32_bf16(
                        al, wh[fn], acc[fm][fn], 0, 0, 0);
                }
            }
        }
    }

#pragma unroll
    for (int fm = 0; fm < 2; fm++)
#pragma unroll
        for (int fn = 0; fn < 4; fn++) {
            int col = wc * 64 + fn * 16 + lr;
#pragma unroll
            for (int q = 0; q < 4; q++) {
                int r = row0 + wr * 32 + fm * 16 + lg * 4 + q;
                out[(size_t)r * 256 + col] = acc[fm][fn][q];
            }
        }
}

// ---------------------------------------------------------------------------
// Small GEMM for x_proj (32 cols), 256 threads (round-5 structure).
// ---------------------------------------------------------------------------
__global__ __launch_bounds__(256) void gemm_nt32(
    const float* A, const float* W, float* out0, int K, int ldo)
{
    __shared__ float As[16][65];
    __shared__ float Ws[16][33];
    const int tid = threadIdx.x;
    const int row0 = blockIdx.x * 64;
    const int tr = (tid / 16) * 4;
    const int tc = (tid % 16) * 2;
    float acc[4][2];
#pragma unroll
    for (int i = 0; i < 4; i++) { acc[i][0] = 0.f; acc[i][1] = 0.f; }
    for (int k0 = 0; k0 < K; k0 += 16) {
        __syncthreads();
        for (int i = tid; i < 64 * 16; i += 256) {
            int m = i / 16, k = i % 16;
            As[k][m] = A[(size_t)(row0 + m) * K + k0 + k];
        }
        for (int i = tid; i < 32 * 16; i += 256) {
            int n = i / 16, k = i % 16;
            Ws[k][n] = W[(size_t)n * K + k0 + k];
        }
        __syncthreads();
#pragma unroll
        for (int kk = 0; kk < 16; kk++) {
            float a[4], b[2];
#pragma unroll
            for (int i = 0; i < 4; i++) a[i] = As[kk][tr + i];
            b[0] = Ws[kk][tc]; b[1] = Ws[kk][tc + 1];
#pragma unroll
            for (int i = 0; i < 4; i++) { acc[i][0] += a[i] * b[0]; acc[i][1] += a[i] * b[1]; }
        }
    }
#pragma unroll
    for (int i = 0; i < 4; i++) {
        int r = row0 + tr + i;
        out0[(size_t)r * ldo + tc] = acc[i][0];
        out0[(size_t)r * ldo + tc + 1] = acc[i][1];
    }
}

// ---------------------------------------------------------------------------
// Selective scan, state-split (round-6 verified).
// ---------------------------------------------------------------------------
__global__ __launch_bounds__(256) void scan_pass1(
    const float* delta_q, const float* u_full, const float* xdbl,
    const float* A_log, int dbase, float* h_end, float* Ssum)
{
    int c = blockIdx.x;
    int tid = threadIdx.x;
    int dl = tid >> 1;
    int sh = (tid & 1) * 8;
    int d = dbase + dl;
    float As[8];
#pragma unroll
    for (int s = 0; s < 8; s++) As[s] = -expf(A_log[d * 16 + sh + s]);
    float h[8];
#pragma unroll
    for (int s = 0; s < 8; s++) h[s] = 0.f;
    float S = 0.f;
    __shared__ float Bs[CHUNK][17];
    int tbase = c * CHUNK;
    for (int i = tid; i < CHUNK * 16; i += 256) {
        int r = i >> 4, s = i & 15;
        Bs[r][s] = xdbl[(size_t)(tbase + r) * 32 + s];
    }
    __syncthreads();
    for (int tl = 0; tl < CHUNK; tl++) {
        size_t t = (size_t)tbase + tl;
        float de = delta_q[t * QCH + dl];
        float uu = u_full[t * DI + d];
        float du = de * uu;
        S += de;
#pragma unroll
        for (int s = 0; s < 8; s++)
            h[s] = __expf(de * As[s]) * h[s] + du * Bs[tl][sh + s];
    }
    size_t base = ((size_t)c * QCH + dl) * 16 + sh;
#pragma unroll
    for (int s = 0; s < 8; s++) h_end[base + s] = h[s];
    if ((tid & 1) == 0) Ssum[(size_t)c * QCH + dl] = S;
}

#define GRP 16
#define NGRP (NCHUNK / GRP)   // 32

__global__ __launch_bounds__(256) void scan_pass2a(
    const float* h_end, const float* Ssum, const float* A_log, int dbase,
    float* Pagg, float* Hagg)
{
    int idx = blockIdx.x * 256 + threadIdx.x;   // 0..2047
    int g = blockIdx.y;                         // 0..31
    int dl = idx >> 4;
    float As = -expf(A_log[(dbase + dl) * 16 + (idx & 15)]);
    float P = 1.f, H = 0.f;
    for (int c = g * GRP; c < g * GRP + GRP; c++) {
        float Pc = __expf(As * Ssum[(size_t)c * QCH + dl]);
        H = Pc * H + h_end[(size_t)c * 2048 + idx];
        P *= Pc;
    }
    Pagg[g * 2048 + idx] = P;
    Hagg[g * 2048 + idx] = H;
}

__global__ __launch_bounds__(256) void scan_pass2b(
    const float* Pagg, const float* Hagg, float* Ginit)
{
    int idx = blockIdx.x * 256 + threadIdx.x;   // 0..2047
    float carry = 0.f;
    for (int g = 0; g < NGRP; g++) {
        Ginit[g * 2048 + idx] = carry;
        carry = Pagg[g * 2048 + idx] * carry + Hagg[g * 2048 + idx];
    }
}

__global__ __launch_bounds__(256) void scan_pass2c(
    const float* h_end, const float* Ssum, const float* A_log, int dbase,
    const float* Ginit, float* initS)
{
    int idx = blockIdx.x * 256 + threadIdx.x;   // 0..2047
    int g = blockIdx.y;                         // 0..31
    int dl = idx >> 4;
    float As = -expf(A_log[(dbase + dl) * 16 + (idx & 15)]);
    float carry = Ginit[g * 2048 + idx];
    for (int c = g * GRP; c < g * GRP + GRP; c++) {
        initS[(size_t)c * 2048 + idx] = carry;
        float Pc = __expf(As * Ssum[(size_t)c * QCH + dl]);
        carry = Pc * carry + h_end[(size_t)c * 2048 + idx];
    }
}

__global__ __launch_bounds__(256) void scan_pass3(
    const float* delta_q, const float* u_full, const float* xdbl,
    const float* A_log, int dbase, const float* initS, const float* Dp,
    float* wg_ymod)
{
    int c = blockIdx.x;
    int tid = threadIdx.x;
    int dl = tid >> 1;
    int sh = (tid & 1) * 8;
    int d = dbase + dl;
    float As[8];
#pragma unroll
    for (int s = 0; s < 8; s++) As[s] = -expf(A_log[d * 16 + sh + s]);
    float h[8];
#pragma unroll
    for (int s = 0; s < 8; s++)
        h[s] = initS[((size_t)c * QCH + dl) * 16 + sh + s];
    float Dd = Dp[d];
    __shared__ float Bs[CHUNK][17];
    __shared__ float Cs[CHUNK][17];
    int tbase = c * CHUNK;
    for (int i = tid; i < CHUNK * 16; i += 256) {
        int r = i >> 4, s = i & 15;
        Bs[r][s] = xdbl[(size_t)(tbase + r) * 32 + s];
        Cs[r][s] = xdbl[(size_t)(tbase + r) * 32 + 16 + s];
    }
    __syncthreads();
    for (int tl = 0; tl < CHUNK; tl++) {
        size_t t = (size_t)tbase + tl;
        float de = delta_q[t * QCH + dl];
        float uu = u_full[t * DI + d];
        float du = de * uu;
        float y = 0.f;
#pragma unroll
        for (int s = 0; s < 8; s++) {
            h[s] = __expf(de * As[s]) * h[s] + du * Bs[tl][sh + s];
            y += h[s] * Cs[tl][sh + s];
        }
        y += __shfl_xor(y, 1);
        if ((tid & 1) == 0)
            wg_ymod[t * DI + d] = (y + Dd * uu) * wg_ymod[t * DI + d];
    }
}

// ---------------------------------------------------------------------------
extern "C" void kernel_launch(void* const* d_in, const int* in_sizes, int n_in,
                              void* d_out, int out_size, void* d_ws, size_t ws_size,
                              hipStream_t stream)
{
    const float* x         = (const float*)d_in[0];
    const float* guidance  = (const float*)d_in[1];
    const float* in_proj_w = (const float*)d_in[2];
    const float* conv_w    = (const float*)d_in[3];
    const float* conv_b    = (const float*)d_in[4];
    const float* x_proj_w  = (const float*)d_in[5];
    const float* dt_proj_w = (const float*)d_in[6];
    const float* dt_proj_b = (const float*)d_in[7];
    const float* gg1_w     = (const float*)d_in[8];
    const float* gg1_b     = (const float*)d_in[9];
    const float* ln_g      = (const float*)d_in[10];
    const float* ln_b      = (const float*)d_in[11];
    const float* gg2_w     = (const float*)d_in[12];
    const float* gg2_b     = (const float*)d_in[13];
    const float* A_log     = (const float*)d_in[14];
    const float* Dp        = (const float*)d_in[15];
    const float* out_proj_w= (const float*)d_in[16];
    float* out = (float*)d_out;

    // ws: two N x 512 fp32 buffers = 256 MiB exactly.
    float* P1 = (float*)d_ws;                    // x_mod (scan u)
    float* P2 = P1 + (size_t)NTOK * DI;          // w_gate -> y_mod (in place)

    // d_out as pre-final scratch (final GEMM overwrites all).
    float* ob      = (float*)d_out;
    float* delta_q = ob;                                  // N x 128   (32 MiB)
    float* xdbl    = ob + (size_t)NTOK * QCH;             // N x 32    (8 MiB)
    float* h_end   = ob + (size_t)NTOK * (QCH + 32);      // 4 MiB
    float* Ssum    = h_end + (size_t)NCHUNK * QCH * DS;   // 0.25 MiB
    float* initS   = Ssum + (size_t)NCHUNK * QCH;         // 4 MiB
    // bf16 hi/lo packet buffers + pass2 aggregates in the free tail of d_out:
    unsigned short* Wg  = (unsigned short*)(initS + (size_t)NCHUNK * QCH * DS);
    unsigned short* Wg2 = Wg  + (size_t)131072 * 8;
    unsigned short* Wdt = Wg2 + (size_t)65536 * 8;
    float* Pagg  = (float*)(Wdt + (size_t)65536 * 8);     // 32x2048 (256 KB)
    float* Hagg  = Pagg + NGRP * 2048;                    // 256 KB
    float* Ginit = Hagg + NGRP * 2048;                    // 256 KB
    // Wout lives in P1's head (dead after the scans); written just-in-time.
    unsigned short* Wout = (unsigned short*)P1;

    // 0. W split-precision preps
    wprep_kernel<<<512, 256, 0, stream>>>(gg2_w, Wg);
    wprep_inproj<<<256, 256, 0, stream>>>(in_proj_w, Wg2);
    wprep_dt<<<256, 256, 0, stream>>>(dt_proj_w, Wdt);
    // 1. in_proj + conv + silu (bf16x3 MFMA) -> P1 = silu(conv(x_in)), P2 = silu(z)
    in_conv_mfma<<<NTOK / 64, 512, 0, stream>>>(
        x, Wg2, conv_w, conv_b, P1, P2);
    // 2. gates (occupancy-doubled bf16x3 MFMA): P1 *= gate_in, P2 *= gate_out
    gates_mfma_kernel<<<dim3(NTOK / 64, 2), 512, 0, stream>>>(
        guidance, gg1_w, gg1_b, ln_g, ln_b, Wg, gg2_b, P1, P2);
    // 3. xdbl = x_mod @ x_proj_w.T  (B|C)
    gemm_nt32<<<NTOK / 64, 256, 0, stream>>>(P1, x_proj_w, xdbl, DI, 32);
    // 4. per 128-channel quarter: delta MFMA GEMM + chunked scan
    for (int q = 0; q < 4; q++) {
        int dbase = q * QCH;
        dtp_mfma<<<NTOK / 64, 512, 0, stream>>>(
            P1, Wdt, dt_proj_b, dbase, delta_q);
        scan_pass1<<<NCHUNK, 256, 0, stream>>>(
            delta_q, P1, xdbl, A_log, dbase, h_end, Ssum);
        scan_pass2a<<<dim3(8, NGRP), 256, 0, stream>>>(
            h_end, Ssum, A_log, dbase, Pagg, Hagg);
        scan_pass2b<<<8, 256, 0, stream>>>(Pagg, Hagg, Ginit);
        scan_pass2c<<<dim3(8, NGRP), 256, 0, stream>>>(
            h_end, Ssum, A_log, dbase, Ginit, initS);
        scan_pass3<<<NCHUNK, 256, 0, stream>>>(
            delta_q, P1, xdbl, A_log, dbase, initS, Dp, P2);
    }
    // 5. out = y_mod @ out_proj_w.T (bf16x3 MFMA; Wout into dead P1 first)
    wprep_out<<<128, 256, 0, stream>>>(out_proj_w, Wout);
    outp_mfma<<<NTOK / 64, 512, 0, stream>>>(P2, Wout, out);
}